// Round 15
// baseline (1406.214 us; speedup 1.0000x reference)
//
#include <hip/hip_runtime.h>
#include <math.h>

#define NPTS   20001
#define NREAL  20000
#define EPAD   1200000
#define KK     64
#define RADF   0.1125f

__device__ __forceinline__ float sgnf(float v){ return v>0.f ? 1.f : (v<0.f ? -1.f : 0.f); }

// ---------------- CSR build (edge_src is sorted; pad edges have dst==NREAL) ----------------
__global__ void k_find_ereal(const int* __restrict__ dst, int* __restrict__ ereal){
  int lo=0, hi=EPAD;
  while(lo<hi){ int mid=(lo+hi)>>1; if(dst[mid]==NREAL) hi=mid; else lo=mid+1; }
  *ereal = lo;
}

__global__ void k_csr(const int* __restrict__ src, const int* __restrict__ erealp,
                      int* __restrict__ row_start){
  int i = blockIdx.x*blockDim.x + threadIdx.x;
  if(i > NPTS) return;
  int E = *erealp;
  int lo=0, hi=E;
  while(lo<hi){ int mid=(lo+hi)>>1; if(src[mid] < i) lo=mid+1; else hi=mid; }
  row_start[i] = lo;
}

__global__ void k_build_f(const float* __restrict__ feats, float* __restrict__ f){
  int idx = blockIdx.x*blockDim.x + threadIdx.x;
  if(idx >= NPTS*13) return;
  int i = idx/13, c = idx - i*13;
  f[idx] = (c==0) ? 1.f : feats[i*12 + (c-1)];
}

// ---------------- per-edge geometry (exact port of ball_to_cube + window) ----------------
__device__ __forceinline__ void edge_geom(float ox, float oy, float oz,
                                          float& win, float& t0, float& t1, float& t2, int& f0p){
  const float eps = 1e-9f;
  float sq = ox*ox + oy*oy + oz*oz;
  float u = 1.f - sq;
  win = fminf(fmaxf(u*u*u, 0.f), 1.f);
  float norm = sqrtf(sq + eps);
  float rxy2 = ox*ox + oy*oy;
  bool polar = (1.25f*oz*oz > rxy2);
  float s_p = sqrtf(3.f*norm/(norm + fabsf(oz) + eps));
  float s_n = norm / sqrtf(rxy2 + eps);
  float s = polar ? s_p : s_n;
  float xc = ox*s, yc = oy*s;
  float zc = polar ? sgnf(oz)*norm : 1.5f*oz;
  if(sq < 1e-12f){ xc = 0.f; yc = 0.f; zc = 0.f; }
  float r = sqrtf(xc*xc + yc*yc + eps);
  bool c1 = fabsf(xc) >= fabsf(yc);
  float xs = (fabsf(xc) < eps) ? eps : xc;
  float ys = (fabsf(yc) < eps) ? eps : yc;
  const float fop = 1.2732395447351628f; // float32(4/pi)
  float a = c1 ? sgnf(xc)*r : sgnf(yc)*r*fop*atanf(xc/ys);
  float b = c1 ? sgnf(xc)*r*fop*atanf(yc/xs) : sgnf(yc)*r;
  if(xc*xc + yc*yc < 1e-12f){ a = 0.f; b = 0.f; }
  float g0 = fminf(fmaxf((a *0.5f+0.5f)*3.f, 0.f), 3.f);
  float g1 = fminf(fmaxf((b *0.5f+0.5f)*3.f, 0.f), 3.f);
  float g2 = fminf(fmaxf((zc*0.5f+0.5f)*3.f, 0.f), 3.f);
  float f00 = floorf(g0), f01 = floorf(g1), f02 = floorf(g2);
  t0 = g0 - f00; t1 = g1 - f01; t2 = g2 - f02;
  f0p = (int)f00 | ((int)f01 << 2) | ((int)f02 << 4);
}

// ---- k_geom: per-edge staged record (32B, ONE cache line), computed ONCE for all layers.
// ge[2e]   = float4{q00,q01,q10,q11}  (win-premultiplied xy-quad weights)
// ge[2e+1] = int4{bits(zA), cells0, cells1, dst}; zB = 1-zA (wz0+wz1==1 exactly).
// min(i+1,3) -> (i+1)&3 is exact (clamped corner has t==0 weight): all 8 cells distinct ->
// batched read/fma/write in the scatters is race-free; parity-p cells owned by wave p.
__global__ __launch_bounds__(256) void k_geom(const float* __restrict__ pos,
    const int* __restrict__ esrc, const int* __restrict__ edst,
    float4* __restrict__ ge)
{
  int e = blockIdx.x*blockDim.x + threadIdx.x;
  if(e >= EPAD) return;
  const int sn = esrc[e], d = edst[e];
  const float ox = (pos[d*3+0]-pos[sn*3+0])/RADF;
  const float oy = (pos[d*3+1]-pos[sn*3+1])/RADF;
  const float oz = (pos[d*3+2]-pos[sn*3+2])/RADF;
  float win, t0, t1, t2; int f0p;
  edge_geom(ox, oy, oz, win, t0, t1, t2, f0p);
  const int i0 = f0p & 3, i1 = (f0p>>2) & 3, i2 = f0p >> 4;
  const int X0 = i0 << 4, X1 = ((i0+1)&3) << 4;
  const int Y0 = i1 << 2, Y1 = ((i1+1)&3) << 2;
  const int Z0 = i2, Z1 = (i2+1) & 3;
  const float wx0 = win*(1.f-t0), wx1 = win*t0;
  const float wy0 = 1.f-t1, wy1 = t1;
  const float wz0 = 1.f-t2, wz1 = t2;
  ge[2*e] = make_float4(wx0*wy0, wx0*wy1, wx1*wy0, wx1*wy1);
  const int p0 = Z0 & 1;
  const float zA = p0 ? wz1 : wz0;                  // weight for parity-0 (even z) cell
  const int   cA = p0 ? Z1 : Z0;                    // even-z cell
  const int   cB = p0 ? Z0 : Z1;                    // odd-z cell
  const int cells0 = (X0|Y0|cA) | ((X0|Y1|cA)<<8) | ((X1|Y0|cA)<<16) | ((X1|Y1|cA)<<24);
  const int cells1 = (X0|Y0|cB) | ((X0|Y1|cB)<<8) | ((X1|Y0|cB)<<16) | ((X1|Y1|cB)<<24);
  ((int4*)ge)[2*e+1] = make_int4(__float_as_int(zA), cells0, cells1, d);
}

// ------- scatter CIN=64: 2 waves (z-parity) x (xbit, channel-pair) lanes, barrier-free.
// lane = xb*32 + p: owns channels {2p,2p+1} and x-corner column xb -> per edge per wave
// only 2 b64 LDS RMWs (cells X_xb|Y0|z and X_xb|Y1|z). Race-free: cells differ across
// xb (X0!=X1) and waves (z parity); same cell => same xb => lanes differ in p.
// OUT3=1: fused cout=3 GEMV epilogue (layer 3).
template<int RELU, int OUT3>
__global__ __launch_bounds__(128) void k_scat64(
    const float* __restrict__ feat, const float4* __restrict__ ge,
    const int* __restrict__ row_start,
    float* __restrict__ B, int node_base,
    const float* __restrict__ W3, float* __restrict__ out)
{
  constexpr int BSZ = 64*64;
  __shared__ __align__(16) float Bl[BSZ];
  __shared__ float red[OUT3 ? 384 : 4];
  const int tid  = threadIdx.x;
  const int node = node_base + blockIdx.x;

  for(int j = tid*4; j < BSZ; j += 512)
    *(float4*)&Bl[j] = make_float4(0.f,0.f,0.f,0.f);

  const int e0 = row_start[node], e1 = row_start[node+1];
  const int wv = tid >> 6;          // z-parity owned by this wave
  const int lane = tid & 63;
  const int xb = lane >> 5;         // x-corner column
  const int p  = lane & 31;         // channel pair: channels 2p, 2p+1
  float2* Bl2 = (float2*)Bl;
  __syncthreads();

  #pragma unroll 2
  for(int e = e0; e < e1; ++e){
    const float4 q  = ge[2*e];
    const int4   md = ((const int4*)ge)[2*e+1];
    const float zA = __int_as_float(md.x);
    const float z  = wv ? (1.f - zA) : zA;
    const int   cp = wv ? md.z : md.y;
    const unsigned sh = xb ? ((unsigned)cp >> 16) : (unsigned)cp;
    const float wA = xb ? q.z : q.x;      // weight for Y0 cell of column xb
    const float wB = xb ? q.w : q.y;      // weight for Y1 cell
    float2 v2 = ((const float2*)(feat + (size_t)md.w*64))[p];
    if(RELU){ v2.x = fmaxf(v2.x,0.f); v2.y = fmaxf(v2.y,0.f); }
    v2.x *= z; v2.y *= z;
    const int a0 = (int)(( sh        & 255u) << 5) + p;   // float2 index: cell*32 + p
    const int a1 = (int)(((sh >> 8)  & 255u) << 5) + p;
    float2 o0 = Bl2[a0], o1 = Bl2[a1];
    o0.x = fmaf(wA, v2.x, o0.x); o0.y = fmaf(wA, v2.y, o0.y);
    o1.x = fmaf(wB, v2.x, o1.x); o1.y = fmaf(wB, v2.y, o1.y);
    Bl2[a0] = o0; Bl2[a1] = o1;
  }
  __syncthreads();

  if(!OUT3){
    float* Bg = B + (size_t)blockIdx.x*BSZ;
    for(int j = tid*4; j < BSZ; j += 512)
      *(float4*)&Bg[j] = *(const float4*)&Bl[j];
  } else {
    float s0=0.f, s1=0.f, s2=0.f;
    for(int j = tid; j < BSZ; j += 128){
      float v = Bl[j];
      s0 = fmaf(v, W3[j*3+0], s0);
      s1 = fmaf(v, W3[j*3+1], s1);
      s2 = fmaf(v, W3[j*3+2], s2);
    }
    float* r0 = red; float* r1 = red+128; float* r2 = red+256;
    r0[tid]=s0; r1[tid]=s1; r2[tid]=s2;
    __syncthreads();
    for(int st = 64; st > 0; st >>= 1){
      if(tid < st){ r0[tid]+=r0[tid+st]; r1[tid]+=r1[tid+st]; r2[tid]+=r2[tid+st]; }
      __syncthreads();
    }
    if(tid == 0 && node < NREAL){
      out[node*3+0] += r0[0]*(1.f/128.f);
      out[node*3+1] += r1[0]*(1.f/128.f);
      out[node*3+2] += r2[0]*(1.f/128.f);
    }
  }
}

// ------- scatter CIN=96: float2 channel pairs (48 lanes), z-parity waves, barrier-free ----
template<int RELU>
__global__ __launch_bounds__(128) void k_scat96(
    const float* __restrict__ feat, const float4* __restrict__ ge,
    const int* __restrict__ row_start,
    float* __restrict__ B, int node_base)
{
  constexpr int CIN = 96, BSZ = KK*CIN, NP = 48;
  __shared__ __align__(16) float Bl[BSZ];
  const int tid  = threadIdx.x;
  const int node = node_base + blockIdx.x;

  for(int j = tid*4; j < BSZ; j += 512)
    *(float4*)&Bl[j] = make_float4(0.f,0.f,0.f,0.f);

  const int e0 = row_start[node], e1 = row_start[node+1];
  const int wv   = tid >> 6;
  const int lane = tid & 63;
  const bool act = (lane < NP);
  float2* Bp2 = (float2*)Bl;
  __syncthreads();

  if(act){
    #pragma unroll 2
    for(int e = e0; e < e1; ++e){
      const float4 q  = ge[2*e];
      const int4   md = ((const int4*)ge)[2*e+1];
      const float zA = __int_as_float(md.x);
      const float z  = wv ? (1.f - zA) : zA;
      const int   cp = wv ? md.z : md.y;
      float2 v2 = ((const float2*)(feat + (size_t)md.w*CIN))[lane];
      if(RELU){ v2.x = fmaxf(v2.x,0.f); v2.y = fmaxf(v2.y,0.f); }
      v2.x *= z; v2.y *= z;
      const int b0 = ( cp        & 255)*NP + lane;
      const int b1 = ((cp >> 8)  & 255)*NP + lane;
      const int b2 = ((cp >> 16) & 255)*NP + lane;
      const int b3 = (((unsigned)cp) >> 24)*NP + lane;
      float2 o0 = Bp2[b0], o1 = Bp2[b1], o2 = Bp2[b2], o3 = Bp2[b3];
      o0.x = fmaf(q.x, v2.x, o0.x); o0.y = fmaf(q.x, v2.y, o0.y);
      o1.x = fmaf(q.y, v2.x, o1.x); o1.y = fmaf(q.y, v2.y, o1.y);
      o2.x = fmaf(q.z, v2.x, o2.x); o2.y = fmaf(q.z, v2.y, o2.y);
      o3.x = fmaf(q.w, v2.x, o3.x); o3.y = fmaf(q.w, v2.y, o3.y);
      Bp2[b0] = o0; Bp2[b1] = o1; Bp2[b2] = o2; Bp2[b3] = o3;
    }
  }
  __syncthreads();

  float* Bg = B + (size_t)blockIdx.x*BSZ;
  for(int j = tid*4; j < BSZ; j += 512)
    *(float4*)&Bg[j] = *(const float4*)&Bl[j];
}

// ------- scatter CIN=13: 4 edge-slots/wave (slot-private copies), z-parity waves ----------
__global__ __launch_bounds__(128) void k_scat13(
    const float* __restrict__ feat, const float4* __restrict__ ge,
    const int* __restrict__ row_start,
    float* __restrict__ B, int node_base)
{
  constexpr int CIN = 13, BSZ = KK*CIN, ESW = 4, CSTRIDE = BSZ + 8;
  __shared__ __align__(16) float Bl[ESW*CSTRIDE];
  const int tid  = threadIdx.x;
  const int node = node_base + blockIdx.x;

  for(int j = tid; j < ESW*CSTRIDE; j += 128) Bl[j] = 0.f;

  const int e0 = row_start[node], e1 = row_start[node+1];
  const int wv   = tid >> 6;
  const int lane = tid & 63;
  const int slot = lane >> 4;
  const int c    = lane & 15;
  const bool act = (c < CIN);
  float* Bp = Bl + slot*CSTRIDE;
  __syncthreads();

  if(act){
    for(int e = e0 + slot; e < e1; e += ESW){
      const float4 q  = ge[2*e];
      const int4   md = ((const int4*)ge)[2*e+1];
      const float zA = __int_as_float(md.x);
      const float z  = wv ? (1.f - zA) : zA;
      const int   cp = wv ? md.z : md.y;
      float v = feat[(size_t)md.w*CIN + c] * z;
      const int b0 = ( cp        & 255)*CIN + c;
      const int b1 = ((cp >> 8)  & 255)*CIN + c;
      const int b2 = ((cp >> 16) & 255)*CIN + c;
      const int b3 = (((unsigned)cp) >> 24)*CIN + c;
      float o0 = Bp[b0], o1 = Bp[b1], o2 = Bp[b2], o3 = Bp[b3];
      o0 = fmaf(q.x, v, o0); o1 = fmaf(q.y, v, o1);
      o2 = fmaf(q.z, v, o2); o3 = fmaf(q.w, v, o3);
      Bp[b0] = o0; Bp[b1] = o1; Bp[b2] = o2; Bp[b3] = o3;
    }
  }
  __syncthreads();

  float* Bg = B + (size_t)blockIdx.x*BSZ;
  for(int j = tid*4; j < BSZ; j += 512){
    float4 a = *(const float4*)&Bl[j];
    #pragma unroll
    for(int k = 1; k < ESW; ++k){
      const float4 t = *(const float4*)&Bl[k*CSTRIDE + j];
      a.x += t.x; a.y += t.y; a.z += t.z; a.w += t.w;
    }
    *(float4*)&Bg[j] = a;
  }
}

// ---- GEMM, no atomics: P[s][node][64] = sum_{k in split s} A[row,k]*W[k,o]
__global__ __launch_bounds__(256) void k_gemm2(
    const float* __restrict__ A, const float* __restrict__ W,
    float* __restrict__ P, int M, int Kd, int node_base, int ktiles_per)
{
  __shared__ __align__(16) float As[16][68];   // [k][row]
  __shared__ __align__(16) float Ws[16][64];   // [k][col]
  const int tid = threadIdx.x;
  const int mbase = blockIdx.x * 64;
  const int s = blockIdx.y;
  const int kt0 = s * ktiles_per * 16;
  const int kt1 = min(Kd, kt0 + ktiles_per*16);
  const int ty = tid >> 4, tx = tid & 15;
  const int arow = tid >> 2, ako = (tid & 3) * 4;
  const int wk = tid >> 4,  wc = (tid & 15) * 4;

  float acc[4][4];
  #pragma unroll
  for(int i=0;i<4;++i)
    #pragma unroll
    for(int j=0;j<4;++j) acc[i][j] = 0.f;

  for(int kt = kt0; kt < kt1; kt += 16){
    float4 av = make_float4(0.f,0.f,0.f,0.f);
    const int grow = mbase + arow;
    if(grow < M) av = *(const float4*)(A + (size_t)grow*Kd + kt + ako);
    const float4 wv = *(const float4*)(W + (size_t)(kt + wk)*64 + wc);
    As[ako+0][arow]=av.x; As[ako+1][arow]=av.y; As[ako+2][arow]=av.z; As[ako+3][arow]=av.w;
    *(float4*)&Ws[wk][wc] = wv;
    __syncthreads();
    #pragma unroll
    for(int kk = 0; kk < 16; ++kk){
      const float4 a = *(const float4*)&As[kk][ty*4];
      const float4 b = *(const float4*)&Ws[kk][tx*4];
      const float aa[4] = {a.x,a.y,a.z,a.w};
      const float bb[4] = {b.x,b.y,b.z,b.w};
      #pragma unroll
      for(int i=0;i<4;++i)
        #pragma unroll
        for(int j=0;j<4;++j) acc[i][j] = fmaf(aa[i], bb[j], acc[i][j]);
    }
    __syncthreads();
  }

  #pragma unroll
  for(int i=0;i<4;++i){
    const int row = mbase + ty*4 + i;
    if(row < M)
      *(float4*)(P + ((size_t)s*NPTS + node_base + row)*64 + tx*4) = *(float4*)&acc[i][0];
  }
}

// ---- combine partials: x[node*ldout+colofs+o] += sum_s P[s][node][o]
template<int S>
__global__ void k_combine(const float* __restrict__ P, float* __restrict__ x,
                          int ldout, int colofs)
{
  int idx = blockIdx.x*blockDim.x + threadIdx.x;
  if(idx >= NPTS*16) return;
  int node = idx >> 4, c4 = (idx & 15) * 4;
  float4 s = *(const float4*)(P + (size_t)node*64 + c4);
  #pragma unroll
  for(int k=1;k<S;++k){
    float4 t = *(const float4*)(P + ((size_t)k*NPTS + node)*64 + c4);
    s.x+=t.x; s.y+=t.y; s.z+=t.z; s.w+=t.w;
  }
  float* xp = x + (size_t)node*ldout + colofs + c4;
  float4 o = *(float4*)xp;
  o.x+=s.x; o.y+=s.y; o.z+=s.z; o.w+=s.w;
  *(float4*)xp = o;
}

// ---------------- dense paths ----------------
__global__ void k_dense0(const float* __restrict__ f, const float* __restrict__ dW,
                         const float* __restrict__ db, const float* __restrict__ cb0,
                         float* __restrict__ out)
{
  int idx = blockIdx.x*blockDim.x + threadIdx.x;
  if(idx >= NPTS*96) return;
  int i = idx/96, c = idx - i*96;
  if(c < 64){ out[idx] = cb0[c]; return; }
  int o = c - 64;
  float s = db[o];
  const float* row = f + (size_t)i*13;
  #pragma unroll
  for(int j=0;j<13;++j) s = fmaf(row[j], dW[j*32+o], s);
  out[idx] = s;
}

template<int CIN>
__global__ void k_dense(const float* __restrict__ in,
                        const float* __restrict__ dW, const float* __restrict__ db,
                        const float* __restrict__ cb, const float* __restrict__ resid,
                        float* __restrict__ out)
{
  int idx = blockIdx.x*blockDim.x + threadIdx.x;
  if(idx >= NPTS*64) return;
  int i = idx >> 6, o = idx & 63;
  float s = db[o] + cb[o];
  if(resid) s += resid[idx];
  const float* row = in + (size_t)i*CIN;
  #pragma unroll 4
  for(int c=0;c<CIN;++c) s = fmaf(fmaxf(row[c],0.f), dW[c*64+o], s);
  out[idx] = s;
}

__global__ void k_dense3(const float* __restrict__ x2, const float* __restrict__ dW,
                         const float* __restrict__ db, const float* __restrict__ cb,
                         float* __restrict__ out)
{
  int idx = blockIdx.x*blockDim.x + threadIdx.x;
  if(idx >= NREAL*3) return;
  int i = idx/3, o = idx - i*3;
  float s = db[o] + cb[o];
  const float* row = x2 + (size_t)i*64;
  for(int c=0;c<64;++c) s = fmaf(fmaxf(row[c],0.f), dW[c*3+o], s);
  out[idx] = s * (1.f/128.f);
}

// ---------------- host ----------------
static inline size_t alup(size_t x){ return (x + 255) & ~(size_t)255; }

static inline int calc_rows(size_t bcap, int cin, int want){
  size_t perrow = (size_t)KK * cin * 4;
  size_t r = (perrow > 0) ? bcap / perrow : 0;
  if(r >= (size_t)want) return want;
  r = (r / 128) * 128;
  if(r < 128) r = 128;
  return (int)r;
}

extern "C" void kernel_launch(void* const* d_in, const int* in_sizes, int n_in,
                              void* d_out, int out_size, void* d_ws, size_t ws_size,
                              hipStream_t stream)
{
  const float* pos   = (const float*)d_in[0];
  const float* feats = (const float*)d_in[1];
  const int*   esrc  = (const int*)d_in[2];
  const int*   edst  = (const int*)d_in[3];
  const float* c0w = (const float*)d_in[4];
  const float* c0b = (const float*)d_in[5];
  const float* d0w = (const float*)d_in[6];
  const float* d0b = (const float*)d_in[7];
  const float* c1w = (const float*)d_in[8];
  const float* c1b = (const float*)d_in[9];
  const float* d1w = (const float*)d_in[10];
  const float* d1b = (const float*)d_in[11];
  const float* c2w = (const float*)d_in[12];
  const float* c2b = (const float*)d_in[13];
  const float* d2w = (const float*)d_in[14];
  const float* d2b = (const float*)d_in[15];
  const float* c3w = (const float*)d_in[16];
  const float* c3b = (const float*)d_in[17];
  const float* d3w = (const float*)d_in[18];
  const float* d3b = (const float*)d_in[19];
  float* out = (float*)d_out;

  char* w = (char*)d_ws;
  size_t off = 0;
  float* f  = (float*)(w+off); off += alup((size_t)NPTS*13*4);
  float* x0 = (float*)(w+off); off += alup((size_t)NPTS*96*4);
  float* x1 = (float*)(w+off); off += alup((size_t)NPTS*64*4);
  float* x2 = (float*)(w+off); off += alup((size_t)NPTS*64*4);
  int* row_start = (int*)(w+off); off += alup((size_t)(NPTS+1)*4);
  int* ereal = (int*)(w+off);     off += alup(16);
  float4* ge = (float4*)(w+off);  off += alup((size_t)EPAD*32);    // per-edge staged record
  float* P  = (float*)(w+off); off += alup((size_t)8*NPTS*64*4);   // split-K partials (S<=8)
  float* B = (float*)(w+off);
  size_t bcap = (ws_size > off) ? (ws_size - off) : 0;

  k_find_ereal<<<1,1,0,stream>>>(edst, ereal);
  k_csr<<<(NPTS+1+255)/256,256,0,stream>>>(esrc, ereal, row_start);
  k_build_f<<<(NPTS*13+255)/256,256,0,stream>>>(feats, f);
  k_geom<<<(EPAD+255)/256,256,0,stream>>>(pos, esrc, edst, ge);

  // ---- layer 0: x0[:,0:64] = cconv0(f)+c0b ; x0[:,64:96] = f@d0w+d0b  (chunk 8192)
  k_dense0<<<(NPTS*96+255)/256,256,0,stream>>>(f, d0w, d0b, c0b, x0);
  {
    int rows = calc_rows(bcap, 13, 8192);
    for(int base = 0; base < NPTS; base += rows){
      int m = (NPTS - base < rows) ? (NPTS - base) : rows;
      k_scat13<<<m,128,0,stream>>>(f, ge, row_start, B, base);
      k_gemm2<<<dim3((m+63)/64, 8),256,0,stream>>>(B, c0w, P, m, 832, base, 7);
    }
    k_combine<8><<<(NPTS*16+255)/256,256,0,stream>>>(P, x0, 96, 0);
  }

  // ---- layer 1: x1 = cconv1(relu(x0)) + relu(x0)@d1w + d1b + c1b   (chunk 4096)
  k_dense<96><<<(NPTS*64+255)/256,256,0,stream>>>(x0, d1w, d1b, c1b, nullptr, x1);
  {
    int rows = calc_rows(bcap, 96, 4096);
    for(int base = 0; base < NPTS; base += rows){
      int m = (NPTS - base < rows) ? (NPTS - base) : rows;
      k_scat96<1><<<m,128,0,stream>>>(x0, ge, row_start, B, base);
      k_gemm2<<<dim3((m+63)/64, 8),256,0,stream>>>(B, c1w, P, m, 6144, base, 48);
    }
    k_combine<8><<<(NPTS*16+255)/256,256,0,stream>>>(P, x1, 64, 0);
  }

  // ---- layer 2: x2 = cconv2(relu(x1)) + relu(x1)@d2w + d2b + c2b + x1  (chunk 4096)
  k_dense<64><<<(NPTS*64+255)/256,256,0,stream>>>(x1, d2w, d2b, c2b, x1, x2);
  {
    int rows = calc_rows(bcap, 64, 4096);
    for(int base = 0; base < NPTS; base += rows){
      int m = (NPTS - base < rows) ? (NPTS - base) : rows;
      k_scat64<1,0><<<m,128,0,stream>>>(x1, ge, row_start, B, base, nullptr, nullptr);
      k_gemm2<<<dim3((m+63)/64, 8),256,0,stream>>>(B, c2w, P, m, 4096, base, 32);
    }
    k_combine<8><<<(NPTS*16+255)/256,256,0,stream>>>(P, x2, 64, 0);
  }

  // ---- layer 3 (fused): out = dense3 part, then scatter adds conv3 GEMV directly
  k_dense3<<<(NREAL*3+255)/256,256,0,stream>>>(x2, d3w, d3b, c3b, out);
  k_scat64<1,1><<<NPTS,128,0,stream>>>(x2, ge, row_start, nullptr, 0, c3w, out);
}

// Round 16
// 1391.932 us; speedup vs baseline: 1.0103x; 1.0103x over previous
//
#include <hip/hip_runtime.h>
#include <math.h>

#define NPTS   20001
#define NREAL  20000
#define EPAD   1200000
#define KK     64
#define RADF   0.1125f

__device__ __forceinline__ float sgnf(float v){ return v>0.f ? 1.f : (v<0.f ? -1.f : 0.f); }

// ---------------- CSR build (edge_src is sorted; pad edges have dst==NREAL) ----------------
__global__ void k_find_ereal(const int* __restrict__ dst, int* __restrict__ ereal){
  int lo=0, hi=EPAD;
  while(lo<hi){ int mid=(lo+hi)>>1; if(dst[mid]==NREAL) hi=mid; else lo=mid+1; }
  *ereal = lo;
}

__global__ void k_csr(const int* __restrict__ src, const int* __restrict__ erealp,
                      int* __restrict__ row_start){
  int i = blockIdx.x*blockDim.x + threadIdx.x;
  if(i > NPTS) return;
  int E = *erealp;
  int lo=0, hi=E;
  while(lo<hi){ int mid=(lo+hi)>>1; if(src[mid] < i) lo=mid+1; else hi=mid; }
  row_start[i] = lo;
}

__global__ void k_build_f(const float* __restrict__ feats, float* __restrict__ f){
  int idx = blockIdx.x*blockDim.x + threadIdx.x;
  if(idx >= NPTS*13) return;
  int i = idx/13, c = idx - i*13;
  f[idx] = (c==0) ? 1.f : feats[i*12 + (c-1)];
}

// ---------------- per-edge geometry (exact port of ball_to_cube + window) ----------------
__device__ __forceinline__ void edge_geom(float ox, float oy, float oz,
                                          float& win, float& t0, float& t1, float& t2, int& f0p){
  const float eps = 1e-9f;
  float sq = ox*ox + oy*oy + oz*oz;
  float u = 1.f - sq;
  win = fminf(fmaxf(u*u*u, 0.f), 1.f);
  float norm = sqrtf(sq + eps);
  float rxy2 = ox*ox + oy*oy;
  bool polar = (1.25f*oz*oz > rxy2);
  float s_p = sqrtf(3.f*norm/(norm + fabsf(oz) + eps));
  float s_n = norm / sqrtf(rxy2 + eps);
  float s = polar ? s_p : s_n;
  float xc = ox*s, yc = oy*s;
  float zc = polar ? sgnf(oz)*norm : 1.5f*oz;
  if(sq < 1e-12f){ xc = 0.f; yc = 0.f; zc = 0.f; }
  float r = sqrtf(xc*xc + yc*yc + eps);
  bool c1 = fabsf(xc) >= fabsf(yc);
  float xs = (fabsf(xc) < eps) ? eps : xc;
  float ys = (fabsf(yc) < eps) ? eps : yc;
  const float fop = 1.2732395447351628f; // float32(4/pi)
  float a = c1 ? sgnf(xc)*r : sgnf(yc)*r*fop*atanf(xc/ys);
  float b = c1 ? sgnf(xc)*r*fop*atanf(yc/xs) : sgnf(yc)*r;
  if(xc*xc + yc*yc < 1e-12f){ a = 0.f; b = 0.f; }
  float g0 = fminf(fmaxf((a *0.5f+0.5f)*3.f, 0.f), 3.f);
  float g1 = fminf(fmaxf((b *0.5f+0.5f)*3.f, 0.f), 3.f);
  float g2 = fminf(fmaxf((zc*0.5f+0.5f)*3.f, 0.f), 3.f);
  float f00 = floorf(g0), f01 = floorf(g1), f02 = floorf(g2);
  t0 = g0 - f00; t1 = g1 - f01; t2 = g2 - f02;
  f0p = (int)f00 | ((int)f01 << 2) | ((int)f02 << 4);
}

// ---- k_geom: per-edge staged record (32B, ONE cache line), computed ONCE for all layers.
// ge[2e]   = float4{q00,q01,q10,q11}  (win-premultiplied xy-quad weights)
// ge[2e+1] = int4{bits(zA), cells0, cells1, dst}; zB = 1-zA (wz0+wz1==1 exactly).
// min(i+1,3) -> (i+1)&3 is exact (clamped corner has t==0 weight): all 8 cells distinct ->
// batched read/fma/write in the scatters is race-free; parity-p cells owned by wave p.
__global__ __launch_bounds__(256) void k_geom(const float* __restrict__ pos,
    const int* __restrict__ esrc, const int* __restrict__ edst,
    float4* __restrict__ ge)
{
  int e = blockIdx.x*blockDim.x + threadIdx.x;
  if(e >= EPAD) return;
  const int sn = esrc[e], d = edst[e];
  const float ox = (pos[d*3+0]-pos[sn*3+0])/RADF;
  const float oy = (pos[d*3+1]-pos[sn*3+1])/RADF;
  const float oz = (pos[d*3+2]-pos[sn*3+2])/RADF;
  float win, t0, t1, t2; int f0p;
  edge_geom(ox, oy, oz, win, t0, t1, t2, f0p);
  const int i0 = f0p & 3, i1 = (f0p>>2) & 3, i2 = f0p >> 4;
  const int X0 = i0 << 4, X1 = ((i0+1)&3) << 4;
  const int Y0 = i1 << 2, Y1 = ((i1+1)&3) << 2;
  const int Z0 = i2, Z1 = (i2+1) & 3;
  const float wx0 = win*(1.f-t0), wx1 = win*t0;
  const float wy0 = 1.f-t1, wy1 = t1;
  const float wz0 = 1.f-t2, wz1 = t2;
  ge[2*e] = make_float4(wx0*wy0, wx0*wy1, wx1*wy0, wx1*wy1);
  const int p0 = Z0 & 1;
  const float zA = p0 ? wz1 : wz0;                  // weight for parity-0 (even z) cell
  const int   cA = p0 ? Z1 : Z0;                    // even-z cell
  const int   cB = p0 ? Z0 : Z1;                    // odd-z cell
  const int cells0 = (X0|Y0|cA) | ((X0|Y1|cA)<<8) | ((X1|Y0|cA)<<16) | ((X1|Y1|cA)<<24);
  const int cells1 = (X0|Y0|cB) | ((X0|Y1|cB)<<8) | ((X1|Y0|cB)<<16) | ((X1|Y1|cB)<<24);
  ((int4*)ge)[2*e+1] = make_int4(__float_as_int(zA), cells0, cells1, d);
}

// ------- scatter CIN=64: 2 waves (z-parity), lane = channel, barrier-free inner loop.
// Round-14 proven body (8x b32 RMW); xbit/float2 remap measured SLOWER (175 vs 165 us).
// OUT3=1: fused cout=3 GEMV epilogue (layer 3).
template<int RELU, int OUT3>
__global__ __launch_bounds__(128) void k_scat64(
    const float* __restrict__ feat, const float4* __restrict__ ge,
    const int* __restrict__ row_start,
    float* __restrict__ B, int node_base,
    const float* __restrict__ W3, float* __restrict__ out)
{
  constexpr int BSZ = 64*64;
  __shared__ __align__(16) float Bl[BSZ];
  __shared__ float red[OUT3 ? 384 : 4];
  const int tid  = threadIdx.x;
  const int node = node_base + blockIdx.x;

  for(int j = tid*4; j < BSZ; j += 512)
    *(float4*)&Bl[j] = make_float4(0.f,0.f,0.f,0.f);

  const int e0 = row_start[node], e1 = row_start[node+1];
  const int wv = tid >> 6;          // z-parity owned by this wave
  const int c  = tid & 63;          // owned channel
  __syncthreads();

  #pragma unroll 2
  for(int e = e0; e < e1; ++e){
    const float4 q  = ge[2*e];
    const int4   md = ((const int4*)ge)[2*e+1];
    const float zA = __int_as_float(md.x);
    const float z  = wv ? (1.f - zA) : zA;
    const int   cp = wv ? md.z : md.y;
    float v = feat[(size_t)md.w*64 + c];
    if(RELU) v = fmaxf(v, 0.f);
    v *= z;
    const int b0 = (( cp        & 255) << 6) + c;
    const int b1 = (((cp >> 8)  & 255) << 6) + c;
    const int b2 = (((cp >> 16) & 255) << 6) + c;
    const int b3 = ((((unsigned)cp) >> 24) << 6) + c;
    float o0 = Bl[b0], o1 = Bl[b1], o2 = Bl[b2], o3 = Bl[b3];
    o0 = fmaf(q.x, v, o0); o1 = fmaf(q.y, v, o1);
    o2 = fmaf(q.z, v, o2); o3 = fmaf(q.w, v, o3);
    Bl[b0] = o0; Bl[b1] = o1; Bl[b2] = o2; Bl[b3] = o3;
  }
  __syncthreads();

  if(!OUT3){
    float* Bg = B + (size_t)blockIdx.x*BSZ;
    for(int j = tid*4; j < BSZ; j += 512)
      *(float4*)&Bg[j] = *(const float4*)&Bl[j];
  } else {
    float s0=0.f, s1=0.f, s2=0.f;
    for(int j = tid; j < BSZ; j += 128){
      float v = Bl[j];
      s0 = fmaf(v, W3[j*3+0], s0);
      s1 = fmaf(v, W3[j*3+1], s1);
      s2 = fmaf(v, W3[j*3+2], s2);
    }
    float* r0 = red; float* r1 = red+128; float* r2 = red+256;
    r0[tid]=s0; r1[tid]=s1; r2[tid]=s2;
    __syncthreads();
    for(int st = 64; st > 0; st >>= 1){
      if(tid < st){ r0[tid]+=r0[tid+st]; r1[tid]+=r1[tid+st]; r2[tid]+=r2[tid+st]; }
      __syncthreads();
    }
    if(tid == 0 && node < NREAL){
      out[node*3+0] += r0[0]*(1.f/128.f);
      out[node*3+1] += r1[0]*(1.f/128.f);
      out[node*3+2] += r2[0]*(1.f/128.f);
    }
  }
}

// ------- scatter CIN=96: float2 channel pairs (48 lanes), z-parity waves, barrier-free ----
template<int RELU>
__global__ __launch_bounds__(128) void k_scat96(
    const float* __restrict__ feat, const float4* __restrict__ ge,
    const int* __restrict__ row_start,
    float* __restrict__ B, int node_base)
{
  constexpr int CIN = 96, BSZ = KK*CIN, NP = 48;
  __shared__ __align__(16) float Bl[BSZ];
  const int tid  = threadIdx.x;
  const int node = node_base + blockIdx.x;

  for(int j = tid*4; j < BSZ; j += 512)
    *(float4*)&Bl[j] = make_float4(0.f,0.f,0.f,0.f);

  const int e0 = row_start[node], e1 = row_start[node+1];
  const int wv   = tid >> 6;
  const int lane = tid & 63;
  const bool act = (lane < NP);
  float2* Bp2 = (float2*)Bl;
  __syncthreads();

  if(act){
    #pragma unroll 2
    for(int e = e0; e < e1; ++e){
      const float4 q  = ge[2*e];
      const int4   md = ((const int4*)ge)[2*e+1];
      const float zA = __int_as_float(md.x);
      const float z  = wv ? (1.f - zA) : zA;
      const int   cp = wv ? md.z : md.y;
      float2 v2 = ((const float2*)(feat + (size_t)md.w*CIN))[lane];
      if(RELU){ v2.x = fmaxf(v2.x,0.f); v2.y = fmaxf(v2.y,0.f); }
      v2.x *= z; v2.y *= z;
      const int b0 = ( cp        & 255)*NP + lane;
      const int b1 = ((cp >> 8)  & 255)*NP + lane;
      const int b2 = ((cp >> 16) & 255)*NP + lane;
      const int b3 = (((unsigned)cp) >> 24)*NP + lane;
      float2 o0 = Bp2[b0], o1 = Bp2[b1], o2 = Bp2[b2], o3 = Bp2[b3];
      o0.x = fmaf(q.x, v2.x, o0.x); o0.y = fmaf(q.x, v2.y, o0.y);
      o1.x = fmaf(q.y, v2.x, o1.x); o1.y = fmaf(q.y, v2.y, o1.y);
      o2.x = fmaf(q.z, v2.x, o2.x); o2.y = fmaf(q.z, v2.y, o2.y);
      o3.x = fmaf(q.w, v2.x, o3.x); o3.y = fmaf(q.w, v2.y, o3.y);
      Bp2[b0] = o0; Bp2[b1] = o1; Bp2[b2] = o2; Bp2[b3] = o3;
    }
  }
  __syncthreads();

  float* Bg = B + (size_t)blockIdx.x*BSZ;
  for(int j = tid*4; j < BSZ; j += 512)
    *(float4*)&Bg[j] = *(const float4*)&Bl[j];
}

// ------- scatter CIN=13: 4 edge-slots/wave (slot-private copies), z-parity waves ----------
__global__ __launch_bounds__(128) void k_scat13(
    const float* __restrict__ feat, const float4* __restrict__ ge,
    const int* __restrict__ row_start,
    float* __restrict__ B, int node_base)
{
  constexpr int CIN = 13, BSZ = KK*CIN, ESW = 4, CSTRIDE = BSZ + 8;
  __shared__ __align__(16) float Bl[ESW*CSTRIDE];
  const int tid  = threadIdx.x;
  const int node = node_base + blockIdx.x;

  for(int j = tid; j < ESW*CSTRIDE; j += 128) Bl[j] = 0.f;

  const int e0 = row_start[node], e1 = row_start[node+1];
  const int wv   = tid >> 6;
  const int lane = tid & 63;
  const int slot = lane >> 4;
  const int c    = lane & 15;
  const bool act = (c < CIN);
  float* Bp = Bl + slot*CSTRIDE;
  __syncthreads();

  if(act){
    for(int e = e0 + slot; e < e1; e += ESW){
      const float4 q  = ge[2*e];
      const int4   md = ((const int4*)ge)[2*e+1];
      const float zA = __int_as_float(md.x);
      const float z  = wv ? (1.f - zA) : zA;
      const int   cp = wv ? md.z : md.y;
      float v = feat[(size_t)md.w*CIN + c] * z;
      const int b0 = ( cp        & 255)*CIN + c;
      const int b1 = ((cp >> 8)  & 255)*CIN + c;
      const int b2 = ((cp >> 16) & 255)*CIN + c;
      const int b3 = (((unsigned)cp) >> 24)*CIN + c;
      float o0 = Bp[b0], o1 = Bp[b1], o2 = Bp[b2], o3 = Bp[b3];
      o0 = fmaf(q.x, v, o0); o1 = fmaf(q.y, v, o1);
      o2 = fmaf(q.z, v, o2); o3 = fmaf(q.w, v, o3);
      Bp[b0] = o0; Bp[b1] = o1; Bp[b2] = o2; Bp[b3] = o3;
    }
  }
  __syncthreads();

  float* Bg = B + (size_t)blockIdx.x*BSZ;
  for(int j = tid*4; j < BSZ; j += 512){
    float4 a = *(const float4*)&Bl[j];
    #pragma unroll
    for(int k = 1; k < ESW; ++k){
      const float4 t = *(const float4*)&Bl[k*CSTRIDE + j];
      a.x += t.x; a.y += t.y; a.z += t.z; a.w += t.w;
    }
    *(float4*)&Bg[j] = a;
  }
}

// ---- GEMM, no atomics: P[s][node][64] = sum_{k in split s} A[row,k]*W[k,o]
__global__ __launch_bounds__(256) void k_gemm2(
    const float* __restrict__ A, const float* __restrict__ W,
    float* __restrict__ P, int M, int Kd, int node_base, int ktiles_per)
{
  __shared__ __align__(16) float As[16][68];   // [k][row]
  __shared__ __align__(16) float Ws[16][64];   // [k][col]
  const int tid = threadIdx.x;
  const int mbase = blockIdx.x * 64;
  const int s = blockIdx.y;
  const int kt0 = s * ktiles_per * 16;
  const int kt1 = min(Kd, kt0 + ktiles_per*16);
  const int ty = tid >> 4, tx = tid & 15;
  const int arow = tid >> 2, ako = (tid & 3) * 4;
  const int wk = tid >> 4,  wc = (tid & 15) * 4;

  float acc[4][4];
  #pragma unroll
  for(int i=0;i<4;++i)
    #pragma unroll
    for(int j=0;j<4;++j) acc[i][j] = 0.f;

  for(int kt = kt0; kt < kt1; kt += 16){
    float4 av = make_float4(0.f,0.f,0.f,0.f);
    const int grow = mbase + arow;
    if(grow < M) av = *(const float4*)(A + (size_t)grow*Kd + kt + ako);
    const float4 wv = *(const float4*)(W + (size_t)(kt + wk)*64 + wc);
    As[ako+0][arow]=av.x; As[ako+1][arow]=av.y; As[ako+2][arow]=av.z; As[ako+3][arow]=av.w;
    *(float4*)&Ws[wk][wc] = wv;
    __syncthreads();
    #pragma unroll
    for(int kk = 0; kk < 16; ++kk){
      const float4 a = *(const float4*)&As[kk][ty*4];
      const float4 b = *(const float4*)&Ws[kk][tx*4];
      const float aa[4] = {a.x,a.y,a.z,a.w};
      const float bb[4] = {b.x,b.y,b.z,b.w};
      #pragma unroll
      for(int i=0;i<4;++i)
        #pragma unroll
        for(int j=0;j<4;++j) acc[i][j] = fmaf(aa[i], bb[j], acc[i][j]);
    }
    __syncthreads();
  }

  #pragma unroll
  for(int i=0;i<4;++i){
    const int row = mbase + ty*4 + i;
    if(row < M)
      *(float4*)(P + ((size_t)s*NPTS + node_base + row)*64 + tx*4) = *(float4*)&acc[i][0];
  }
}

// ---- combine partials: x[node*ldout+colofs+o] += sum_s P[s][node][o]
template<int S>
__global__ void k_combine(const float* __restrict__ P, float* __restrict__ x,
                          int ldout, int colofs)
{
  int idx = blockIdx.x*blockDim.x + threadIdx.x;
  if(idx >= NPTS*16) return;
  int node = idx >> 4, c4 = (idx & 15) * 4;
  float4 s = *(const float4*)(P + (size_t)node*64 + c4);
  #pragma unroll
  for(int k=1;k<S;++k){
    float4 t = *(const float4*)(P + ((size_t)k*NPTS + node)*64 + c4);
    s.x+=t.x; s.y+=t.y; s.z+=t.z; s.w+=t.w;
  }
  float* xp = x + (size_t)node*ldout + colofs + c4;
  float4 o = *(float4*)xp;
  o.x+=s.x; o.y+=s.y; o.z+=s.z; o.w+=s.w;
  *(float4*)xp = o;
}

// ---------------- dense paths ----------------
__global__ void k_dense0(const float* __restrict__ f, const float* __restrict__ dW,
                         const float* __restrict__ db, const float* __restrict__ cb0,
                         float* __restrict__ out)
{
  int idx = blockIdx.x*blockDim.x + threadIdx.x;
  if(idx >= NPTS*96) return;
  int i = idx/96, c = idx - i*96;
  if(c < 64){ out[idx] = cb0[c]; return; }
  int o = c - 64;
  float s = db[o];
  const float* row = f + (size_t)i*13;
  #pragma unroll
  for(int j=0;j<13;++j) s = fmaf(row[j], dW[j*32+o], s);
  out[idx] = s;
}

template<int CIN>
__global__ void k_dense(const float* __restrict__ in,
                        const float* __restrict__ dW, const float* __restrict__ db,
                        const float* __restrict__ cb, const float* __restrict__ resid,
                        float* __restrict__ out)
{
  int idx = blockIdx.x*blockDim.x + threadIdx.x;
  if(idx >= NPTS*64) return;
  int i = idx >> 6, o = idx & 63;
  float s = db[o] + cb[o];
  if(resid) s += resid[idx];
  const float* row = in + (size_t)i*CIN;
  #pragma unroll 4
  for(int c=0;c<CIN;++c) s = fmaf(fmaxf(row[c],0.f), dW[c*64+o], s);
  out[idx] = s;
}

__global__ void k_dense3(const float* __restrict__ x2, const float* __restrict__ dW,
                         const float* __restrict__ db, const float* __restrict__ cb,
                         float* __restrict__ out)
{
  int idx = blockIdx.x*blockDim.x + threadIdx.x;
  if(idx >= NREAL*3) return;
  int i = idx/3, o = idx - i*3;
  float s = db[o] + cb[o];
  const float* row = x2 + (size_t)i*64;
  for(int c=0;c<64;++c) s = fmaf(fmaxf(row[c],0.f), dW[c*3+o], s);
  out[idx] = s * (1.f/128.f);
}

// ---------------- host ----------------
static inline size_t alup(size_t x){ return (x + 255) & ~(size_t)255; }

static inline int calc_rows(size_t bcap, int cin, int want){
  size_t perrow = (size_t)KK * cin * 4;
  size_t r = (perrow > 0) ? bcap / perrow : 0;
  if(r >= (size_t)want) return want;
  r = (r / 128) * 128;
  if(r < 128) r = 128;
  return (int)r;
}

extern "C" void kernel_launch(void* const* d_in, const int* in_sizes, int n_in,
                              void* d_out, int out_size, void* d_ws, size_t ws_size,
                              hipStream_t stream)
{
  const float* pos   = (const float*)d_in[0];
  const float* feats = (const float*)d_in[1];
  const int*   esrc  = (const int*)d_in[2];
  const int*   edst  = (const int*)d_in[3];
  const float* c0w = (const float*)d_in[4];
  const float* c0b = (const float*)d_in[5];
  const float* d0w = (const float*)d_in[6];
  const float* d0b = (const float*)d_in[7];
  const float* c1w = (const float*)d_in[8];
  const float* c1b = (const float*)d_in[9];
  const float* d1w = (const float*)d_in[10];
  const float* d1b = (const float*)d_in[11];
  const float* c2w = (const float*)d_in[12];
  const float* c2b = (const float*)d_in[13];
  const float* d2w = (const float*)d_in[14];
  const float* d2b = (const float*)d_in[15];
  const float* c3w = (const float*)d_in[16];
  const float* c3b = (const float*)d_in[17];
  const float* d3w = (const float*)d_in[18];
  const float* d3b = (const float*)d_in[19];
  float* out = (float*)d_out;

  char* w = (char*)d_ws;
  size_t off = 0;
  float* f  = (float*)(w+off); off += alup((size_t)NPTS*13*4);
  float* x0 = (float*)(w+off); off += alup((size_t)NPTS*96*4);
  float* x1 = (float*)(w+off); off += alup((size_t)NPTS*64*4);
  float* x2 = (float*)(w+off); off += alup((size_t)NPTS*64*4);
  int* row_start = (int*)(w+off); off += alup((size_t)(NPTS+1)*4);
  int* ereal = (int*)(w+off);     off += alup(16);
  float4* ge = (float4*)(w+off);  off += alup((size_t)EPAD*32);    // per-edge staged record
  float* P  = (float*)(w+off); off += alup((size_t)8*NPTS*64*4);   // split-K partials (S<=8)
  float* B = (float*)(w+off);
  size_t bcap = (ws_size > off) ? (ws_size - off) : 0;

  k_find_ereal<<<1,1,0,stream>>>(edst, ereal);
  k_csr<<<(NPTS+1+255)/256,256,0,stream>>>(esrc, ereal, row_start);
  k_build_f<<<(NPTS*13+255)/256,256,0,stream>>>(feats, f);
  k_geom<<<(EPAD+255)/256,256,0,stream>>>(pos, esrc, edst, ge);

  // ---- layer 0: x0[:,0:64] = cconv0(f)+c0b ; x0[:,64:96] = f@d0w+d0b  (chunk 8192)
  k_dense0<<<(NPTS*96+255)/256,256,0,stream>>>(f, d0w, d0b, c0b, x0);
  {
    int rows = calc_rows(bcap, 13, 8192);
    for(int base = 0; base < NPTS; base += rows){
      int m = (NPTS - base < rows) ? (NPTS - base) : rows;
      k_scat13<<<m,128,0,stream>>>(f, ge, row_start, B, base);
      k_gemm2<<<dim3((m+63)/64, 8),256,0,stream>>>(B, c0w, P, m, 832, base, 7);
    }
    k_combine<8><<<(NPTS*16+255)/256,256,0,stream>>>(P, x0, 96, 0);
  }

  // ---- layer 1: x1 = cconv1(relu(x0)) + relu(x0)@d1w + d1b + c1b   (chunk 4096)
  k_dense<96><<<(NPTS*64+255)/256,256,0,stream>>>(x0, d1w, d1b, c1b, nullptr, x1);
  {
    int rows = calc_rows(bcap, 96, 4096);
    for(int base = 0; base < NPTS; base += rows){
      int m = (NPTS - base < rows) ? (NPTS - base) : rows;
      k_scat96<1><<<m,128,0,stream>>>(x0, ge, row_start, B, base);
      k_gemm2<<<dim3((m+63)/64, 8),256,0,stream>>>(B, c1w, P, m, 6144, base, 48);
    }
    k_combine<8><<<(NPTS*16+255)/256,256,0,stream>>>(P, x1, 64, 0);
  }

  // ---- layer 2: x2 = cconv2(relu(x1)) + relu(x1)@d2w + d2b + c2b + x1  (chunk 4096)
  k_dense<64><<<(NPTS*64+255)/256,256,0,stream>>>(x1, d2w, d2b, c2b, x1, x2);
  {
    int rows = calc_rows(bcap, 64, 4096);
    for(int base = 0; base < NPTS; base += rows){
      int m = (NPTS - base < rows) ? (NPTS - base) : rows;
      k_scat64<1,0><<<m,128,0,stream>>>(x1, ge, row_start, B, base, nullptr, nullptr);
      k_gemm2<<<dim3((m+63)/64, 8),256,0,stream>>>(B, c2w, P, m, 4096, base, 32);
    }
    k_combine<8><<<(NPTS*16+255)/256,256,0,stream>>>(P, x2, 64, 0);
  }

  // ---- layer 3 (fused): out = dense3 part, then scatter adds conv3 GEMV directly
  k_dense3<<<(NREAL*3+255)/256,256,0,stream>>>(x2, d3w, d3b, c3b, out);
  k_scat64<1,1><<<NPTS,128,0,stream>>>(x2, ge, row_start, nullptr, 0, c3w, out);
}